// Round 6
// baseline (145011.450 us; speedup 1.0000x reference)
//
#include <hip/hip_runtime.h>
#include <math.h>

#define NHD 850
#define LDP 1700
#define SSZ (256 * 850)
#define KP0 1728                       // K=1700 padded to 32
#define KP1 864                        // K=850 padded to 32
#define PST ((size_t)(256 * 1700))     // one split-K partial slice (floats)
#define WES ((size_t)1700 * KP1)       // elems per transposed edge weight
#define SBSZ ((size_t)256 * KP1)       // one bf16 state buffer (padded)
#define NBLK 224                       // 56 tiles x 4 splits (<=256 CUs: co-resident)

typedef float f32x4 __attribute__((ext_vector_type(4)));
typedef short short8 __attribute__((ext_vector_type(8)));

__device__ __forceinline__ int imin(int a, int b) { return a < b ? a : b; }
__device__ __forceinline__ unsigned short f2bf(float x) {
  unsigned u = __float_as_uint(x);
  u += 0x7fff + ((u >> 16) & 1);       // RNE
  return (unsigned short)(u >> 16);
}
__device__ __forceinline__ float bf2f(unsigned short b) {
  return __uint_as_float(((unsigned)b) << 16);
}
__device__ __forceinline__ float sigf(float x) { return 1.0f / (1.0f + expf(-x)); }
__device__ __forceinline__ float actf(int a, float x) {
  switch (a) {
    case 0: return tanhf(x);
    case 1: return fmaxf(x, 0.0f);
    case 2: return sigf(x);
    default: return x;
  }
}

#define MFMA(a, b, c) __builtin_amdgcn_mfma_f32_16x16x32_bf16(a, b, c, 0, 0, 0)

struct Shm {
  unsigned short A[2][64][40];         // [prec][row][k]
  unsigned short W[2][2][64][40];      // [c/h][prec][col][k]
};

// ---------------- weight split+transpose: in[K][N] fp32 -> hi/lo [N][KPad] bf16
struct TransCfg {
  const float* in; unsigned short* oh; unsigned short* ol;
  long inStride, outStride;
  int K, N, KPad;
};

__global__ __launch_bounds__(256) void k_wsplit(TransCfg c) {
  const float* in = c.in + (size_t)blockIdx.z * c.inStride;
  unsigned short* oh = c.oh + (size_t)blockIdx.z * c.outStride;
  unsigned short* ol = c.ol + (size_t)blockIdx.z * c.outStride;
  __shared__ float tile[32][33];
  const int tx = threadIdx.x, ty = threadIdx.y;       // (32,8)
  const int k0 = blockIdx.x * 32, n0 = blockIdx.y * 32;
  #pragma unroll
  for (int i = 0; i < 4; ++i) {
    int k = k0 + ty + i * 8, n = n0 + tx;
    tile[ty + i * 8][tx] = (k < c.K && n < c.N) ? in[(size_t)k * c.N + n] : 0.f;
  }
  __syncthreads();
  #pragma unroll
  for (int i = 0; i < 4; ++i) {
    int n = n0 + ty + i * 8, k = k0 + tx;
    if (n < c.N && k < c.KPad) {
      float v = tile[tx][ty + i * 8];
      unsigned short h = f2bf(v);
      oh[(size_t)n * c.KPad + k] = h;
      ol[(size_t)n * c.KPad + k] = f2bf(v - bf2f(h));
    }
  }
}

__global__ void k_init(int* bar, int* cnt) {
  if (threadIdx.x == 0) *bar = 0;
  cnt[threadIdx.x] = 0;
}

// ---------------- sync primitives
__device__ __forceinline__ void gbar(int* bar, int target) {
  __threadfence();
  __syncthreads();
  if (threadIdx.x == 0) {
    __hip_atomic_fetch_add(bar, 1, __ATOMIC_RELEASE, __HIP_MEMORY_SCOPE_AGENT);
    while (__hip_atomic_load(bar, __ATOMIC_ACQUIRE, __HIP_MEMORY_SCOPE_AGENT) < target)
      __builtin_amdgcn_s_sleep(2);
  }
  __syncthreads();
  __threadfence();
}

__device__ __forceinline__ bool lastArrive(int* c, int need) {
  __shared__ int lastFlag;
  __threadfence();
  __syncthreads();
  if (threadIdx.x == 0) {
    int old = __hip_atomic_fetch_add(c, 1, __ATOMIC_ACQ_REL, __HIP_MEMORY_SCOPE_AGENT);
    lastFlag = (old == need - 1);
    if (lastFlag) __hip_atomic_store(c, 0, __ATOMIC_RELAXED, __HIP_MEMORY_SCOPE_AGENT);
  }
  __syncthreads();
  bool last = (lastFlag != 0);
  if (last) __threadfence();           // acquire: see other blocks' partials
  return last;
}

// ---------------- GEMM chunk over bf16 hi/lo A (KP1 stride)
__device__ __forceinline__ void gemm_bf(Shm& sh,
    const unsigned short* Ahi, const unsigned short* Alo,
    const unsigned short* Wh, const unsigned short* Wl,
    int i0, int i1, int row0, int col0, f32x4 accC[2][2], f32x4 accH[2][2])
{
  const int tid = threadIdx.x;
  const int ar = tid >> 2, a8 = (tid & 3) << 3;
  const int lane = tid & 63, wid = tid >> 6;
  const int wr = wid >> 1, wc = wid & 1;
  const int lrow = lane & 15, lk = (lane >> 4) << 3;
  for (int it = i0; it < i1; ++it) {
    const int kt = it * 32;
    { const size_t o = (size_t)(row0 + ar) * KP1 + kt + a8;
      *(short8*)&sh.A[0][ar][a8] = *(const short8*)(Ahi + o);
      *(short8*)&sh.A[1][ar][a8] = *(const short8*)(Alo + o); }
    { const int colw = col0 + ar;
      if (colw < NHD) {
        const size_t oc = (size_t)colw * KP1 + kt + a8;
        const size_t oh = (size_t)(NHD + colw) * KP1 + kt + a8;
        *(short8*)&sh.W[0][0][ar][a8] = *(const short8*)(Wh + oc);
        *(short8*)&sh.W[0][1][ar][a8] = *(const short8*)(Wl + oc);
        *(short8*)&sh.W[1][0][ar][a8] = *(const short8*)(Wh + oh);
        *(short8*)&sh.W[1][1][ar][a8] = *(const short8*)(Wl + oh);
      } else {
        short8 z = {};
        *(short8*)&sh.W[0][0][ar][a8] = z; *(short8*)&sh.W[0][1][ar][a8] = z;
        *(short8*)&sh.W[1][0][ar][a8] = z; *(short8*)&sh.W[1][1][ar][a8] = z;
      } }
    __syncthreads();
    short8 aF0[2], aF1[2];
    #pragma unroll
    for (int rt = 0; rt < 2; ++rt) {
      aF0[rt] = *(const short8*)&sh.A[0][wr * 32 + rt * 16 + lrow][lk];
      aF1[rt] = *(const short8*)&sh.A[1][wr * 32 + rt * 16 + lrow][lk];
    }
    #pragma unroll
    for (int ct = 0; ct < 2; ++ct) {
      const int colf = wc * 32 + ct * 16 + lrow;
      short8 cH = *(const short8*)&sh.W[0][0][colf][lk];
      short8 cL = *(const short8*)&sh.W[0][1][colf][lk];
      short8 hH = *(const short8*)&sh.W[1][0][colf][lk];
      short8 hL = *(const short8*)&sh.W[1][1][colf][lk];
      #pragma unroll
      for (int rt = 0; rt < 2; ++rt) {
        accC[rt][ct] = MFMA(aF0[rt], cH, accC[rt][ct]);
        accC[rt][ct] = MFMA(aF1[rt], cH, accC[rt][ct]);
        accC[rt][ct] = MFMA(aF0[rt], cL, accC[rt][ct]);
        accH[rt][ct] = MFMA(aF0[rt], hH, accH[rt][ct]);
        accH[rt][ct] = MFMA(aF1[rt], hH, accH[rt][ct]);
        accH[rt][ct] = MFMA(aF0[rt], hL, accH[rt][ct]);
      }
    }
    __syncthreads();
  }
}

// ---------------- s0 GEMM chunk: A = [x | h] fp32, split on the fly (KP0 W stride)
__device__ __forceinline__ void gemm_s0(Shm& sh,
    const float* X, const float* H,
    const unsigned short* Wh, const unsigned short* Wl,
    int i0, int i1, int row0, int col0, f32x4 accC[2][2], f32x4 accH[2][2])
{
  const int tid = threadIdx.x;
  const int ar = tid >> 2, a8 = (tid & 3) << 3;
  const int lane = tid & 63, wid = tid >> 6;
  const int wr = wid >> 1, wc = wid & 1;
  const int lrow = lane & 15, lk = (lane >> 4) << 3;
  for (int it = i0; it < i1; ++it) {
    const int kt = it * 32;
    {
      const int r = row0 + ar, kb = kt + a8;
      float v[8];
      if (kb + 8 <= NHD) {
        const float2* p = (const float2*)(X + (size_t)r * NHD + kb);
        float2 x0 = p[0], x1 = p[1], x2 = p[2], x3 = p[3];
        v[0]=x0.x; v[1]=x0.y; v[2]=x1.x; v[3]=x1.y;
        v[4]=x2.x; v[5]=x2.y; v[6]=x3.x; v[7]=x3.y;
      } else if (kb >= NHD && kb + 8 <= 1700) {
        const float2* p = (const float2*)(H + (size_t)r * NHD + (kb - NHD));
        float2 x0 = p[0], x1 = p[1], x2 = p[2], x3 = p[3];
        v[0]=x0.x; v[1]=x0.y; v[2]=x1.x; v[3]=x1.y;
        v[4]=x2.x; v[5]=x2.y; v[6]=x3.x; v[7]=x3.y;
      } else {
        #pragma unroll
        for (int j = 0; j < 8; ++j) {
          int k = kb + j; float x = 0.f;
          if (k < NHD) x = X[(size_t)r * NHD + k];
          else if (k < 1700) x = H[(size_t)r * NHD + (k - NHD)];
          v[j] = x;
        }
      }
      short8 hi8, lo8;
      #pragma unroll
      for (int j = 0; j < 8; ++j) {
        unsigned short h = f2bf(v[j]);
        hi8[j] = (short)h;
        lo8[j] = (short)f2bf(v[j] - bf2f(h));
      }
      *(short8*)&sh.A[0][ar][a8] = hi8;
      *(short8*)&sh.A[1][ar][a8] = lo8;
    }
    { const int colw = col0 + ar;
      if (colw < NHD) {
        const size_t oc = (size_t)colw * KP0 + kt + a8;
        const size_t oh = (size_t)(NHD + colw) * KP0 + kt + a8;
        *(short8*)&sh.W[0][0][ar][a8] = *(const short8*)(Wh + oc);
        *(short8*)&sh.W[0][1][ar][a8] = *(const short8*)(Wl + oc);
        *(short8*)&sh.W[1][0][ar][a8] = *(const short8*)(Wh + oh);
        *(short8*)&sh.W[1][1][ar][a8] = *(const short8*)(Wl + oh);
      } else {
        short8 z = {};
        *(short8*)&sh.W[0][0][ar][a8] = z; *(short8*)&sh.W[0][1][ar][a8] = z;
        *(short8*)&sh.W[1][0][ar][a8] = z; *(short8*)&sh.W[1][1][ar][a8] = z;
      } }
    __syncthreads();
    short8 aF0[2], aF1[2];
    #pragma unroll
    for (int rt = 0; rt < 2; ++rt) {
      aF0[rt] = *(const short8*)&sh.A[0][wr * 32 + rt * 16 + lrow][lk];
      aF1[rt] = *(const short8*)&sh.A[1][wr * 32 + rt * 16 + lrow][lk];
    }
    #pragma unroll
    for (int ct = 0; ct < 2; ++ct) {
      const int colf = wc * 32 + ct * 16 + lrow;
      short8 cH = *(const short8*)&sh.W[0][0][colf][lk];
      short8 cL = *(const short8*)&sh.W[0][1][colf][lk];
      short8 hH = *(const short8*)&sh.W[1][0][colf][lk];
      short8 hL = *(const short8*)&sh.W[1][1][colf][lk];
      #pragma unroll
      for (int rt = 0; rt < 2; ++rt) {
        accC[rt][ct] = MFMA(aF0[rt], cH, accC[rt][ct]);
        accC[rt][ct] = MFMA(aF1[rt], cH, accC[rt][ct]);
        accC[rt][ct] = MFMA(aF0[rt], cL, accC[rt][ct]);
        accH[rt][ct] = MFMA(aF0[rt], hH, accH[rt][ct]);
        accH[rt][ct] = MFMA(aF1[rt], hH, accH[rt][ct]);
        accH[rt][ct] = MFMA(aF0[rt], hL, accH[rt][ct]);
      }
    }
    __syncthreads();
  }
}

// ---------------- store split-K partial slice
__device__ __forceinline__ void writeP(float* Pslice, int row0, int col0,
                                       const f32x4 accC[2][2], const f32x4 accH[2][2]) {
  const int tid = threadIdx.x;
  const int lane = tid & 63, wid = tid >> 6;
  const int wr = wid >> 1, wc = wid & 1;
  const int lrow = lane & 15;
  #pragma unroll
  for (int rt = 0; rt < 2; ++rt)
  #pragma unroll
  for (int ct = 0; ct < 2; ++ct) {
    const int colb = col0 + wc * 32 + ct * 16 + lrow;
    if (colb < NHD) {
      #pragma unroll
      for (int q = 0; q < 4; ++q) {
        const int row = row0 + wr * 32 + rt * 16 + ((lane >> 4) << 2) + q;
        Pslice[(size_t)row * LDP + colb]       = accC[rt][ct][q];
        Pslice[(size_t)row * LDP + NHD + colb] = accH[rt][ct][q];
      }
    }
  }
}

// ---------------- last-block reduce: sum slices, gate, write fp32 + bf16 hi/lo
__device__ __forceinline__ void reduce_gate(
    const float* Pbase, int nsplit, const float* pred, int act,
    float* SfO, unsigned* hiO, unsigned* loO, int row0, int col0)
{
  const int tid = threadIdx.x;
  const int r = row0 + (tid >> 2);
  const int c0 = col0 + (tid & 3) * 16;
  float cv[16], hv[16];
  #pragma unroll
  for (int j = 0; j < 16; ++j) { cv[j] = 0.f; hv[j] = 0.f; }
  for (int s = 0; s < nsplit; ++s) {
    const float* Pr = Pbase + (size_t)s * PST + (size_t)r * LDP;
    #pragma unroll
    for (int j = 0; j < 8; ++j) {
      int c = c0 + j * 2;
      if (c < NHD) {
        float2 x = *(const float2*)(Pr + c);
        float2 y = *(const float2*)(Pr + NHD + c);
        cv[2*j] += x.x; cv[2*j+1] += x.y;
        hv[2*j] += y.x; hv[2*j+1] += y.y;
      }
    }
  }
  float o[16];
  #pragma unroll
  for (int j = 0; j < 16; ++j) {
    int c = c0 + j;
    if (c < NHD) {
      float p = pred[(size_t)r * NHD + c];
      o[j] = p + sigf(cv[j]) * (actf(act, hv[j]) - p);
    } else o[j] = 0.f;
  }
  #pragma unroll
  for (int j = 0; j < 8; ++j) {
    int c = c0 + j * 2;
    if (c < NHD) *(float2*)(SfO + (size_t)r * NHD + c) = make_float2(o[2*j], o[2*j+1]);
  }
  if (hiO) {
    #pragma unroll
    for (int j = 0; j < 8; ++j) {
      int c = c0 + j * 2;
      if (c < KP1) {
        unsigned hw = 0, lw = 0;
        if (c < NHD) {
          unsigned short hx = f2bf(o[2*j]), hy = f2bf(o[2*j+1]);
          unsigned short lx = f2bf(o[2*j] - bf2f(hx)), ly = f2bf(o[2*j+1] - bf2f(hy));
          hw = (unsigned)hx | ((unsigned)hy << 16);
          lw = (unsigned)lx | ((unsigned)ly << 16);
        }
        hiO[(size_t)r * (KP1/2) + (c >> 1)] = hw;
        loO[(size_t)r * (KP1/2) + (c >> 1)] = lw;
      }
    }
  }
}

// ---------------- final: gate e5 (sig, slices 0-1) + e7 (relu, slices 2-3), mean
__device__ __forceinline__ void reduce_fin(const float* P,
    const float* S1f, const float* S2f, const float* S3f, const float* S4f,
    const float* S5f, const float* S7f, float* ot, float* tail,
    int row0, int col0)
{
  const int tid = threadIdx.x;
  const int r = row0 + (tid >> 2);
  const int c0 = col0 + (tid & 3) * 16;
  float c5[16], h5[16], c7[16], h7[16];
  #pragma unroll
  for (int j = 0; j < 16; ++j) { c5[j]=0.f; h5[j]=0.f; c7[j]=0.f; h7[j]=0.f; }
  for (int s = 0; s < 2; ++s) {
    const float* P5 = P + (size_t)s * PST + (size_t)r * LDP;
    const float* P7 = P + (size_t)(2 + s) * PST + (size_t)r * LDP;
    #pragma unroll
    for (int j = 0; j < 8; ++j) {
      int c = c0 + j * 2;
      if (c < NHD) {
        float2 a = *(const float2*)(P5 + c);
        float2 b = *(const float2*)(P5 + NHD + c);
        float2 x = *(const float2*)(P7 + c);
        float2 y = *(const float2*)(P7 + NHD + c);
        c5[2*j] += a.x; c5[2*j+1] += a.y; h5[2*j] += b.x; h5[2*j+1] += b.y;
        c7[2*j] += x.x; c7[2*j+1] += x.y; h7[2*j] += y.x; h7[2*j+1] += y.y;
      }
    }
  }
  #pragma unroll
  for (int j = 0; j < 8; ++j) {
    int c = c0 + j * 2;
    if (c < NHD) {
      const size_t oo = (size_t)r * NHD + c;
      float2 p5 = *(const float2*)(S5f + oo);
      float2 v1 = *(const float2*)(S1f + oo), v2 = *(const float2*)(S2f + oo);
      float2 v3 = *(const float2*)(S3f + oo), v4 = *(const float2*)(S4f + oo);
      float2 v7 = *(const float2*)(S7f + oo);
      float s6x = p5.x + sigf(c5[2*j]) * (sigf(h5[2*j]) - p5.x);
      float s6y = p5.y + sigf(c5[2*j+1]) * (sigf(h5[2*j+1]) - p5.y);
      float s8x = p5.x + sigf(c7[2*j]) * (fmaxf(h7[2*j], 0.f) - p5.x);
      float s8y = p5.y + sigf(c7[2*j+1]) * (fmaxf(h7[2*j+1], 0.f) - p5.y);
      float2 m;
      m.x = (v1.x + v2.x + v3.x + v4.x + p5.x + s6x + v7.x + s8x) * 0.125f;
      m.y = (v1.y + v2.y + v3.y + v4.y + p5.y + s6y + v7.y + s8y) * 0.125f;
      *(float2*)(ot + oo) = m;
      if (tail) *(float2*)(tail + oo) = m;
    }
  }
}

// ---------------- the whole 70-step recurrence in ONE launch
struct MegaArgs {
  const float *X, *h0; float* out;
  const unsigned short *W0h, *W0l, *Wsh, *Wsl;
  float* Sf; unsigned short *Shi, *Slo;
  float* P; int *bar, *cnt;
};

__global__ __launch_bounds__(256) void k_mega(MegaArgs a) {
  __shared__ Shm sh;
  const int tile = blockIdx.x, by = blockIdx.y;     // 56 x 4
  const int row0 = (tile / 14) * 64, col0 = (tile % 14) * 64;

  float* S0f = a.Sf;                 float* S1f = a.Sf + 1 * (size_t)SSZ;
  float* S2f = a.Sf + 2 * (size_t)SSZ; float* S3f = a.Sf + 3 * (size_t)SSZ;
  float* S4f = a.Sf + 4 * (size_t)SSZ; float* S5f = a.Sf + 5 * (size_t)SSZ;
  float* S7f = a.Sf + 6 * (size_t)SSZ;
  unsigned short* S0hi = a.Shi;                  unsigned short* S0lo = a.Slo;
  unsigned short* S1hi = a.Shi + 1 * SBSZ;       unsigned short* S1lo = a.Slo + 1 * SBSZ;
  unsigned short* S2hi = a.Shi + 2 * SBSZ;       unsigned short* S2lo = a.Slo + 2 * SBSZ;
  unsigned short* S3hi = a.Shi + 3 * SBSZ;       unsigned short* S3lo = a.Slo + 3 * SBSZ;
  unsigned short* S5hi = a.Shi + 4 * SBSZ;       unsigned short* S5lo = a.Slo + 4 * SBSZ;

  int barT = 0;
  for (int t = 0; t < 70; ++t) {
    const float* xt = a.X + (size_t)t * SSZ;
    const float* hp = t ? a.out + (size_t)(t - 1) * SSZ : a.h0;

    { // ---- stage 0: s0 = gate([x|h] @ W0), K=1700, split x4 {14,14,13,13}
      f32x4 aC[2][2] = {}, aH[2][2] = {};
      int i0 = by * 13 + imin(by, 2), len = 13 + (by < 2 ? 1 : 0);
      gemm_s0(sh, xt, hp, a.W0h, a.W0l, i0, i0 + len, row0, col0, aC, aH);
      writeP(a.P + (size_t)by * PST, row0, col0, aC, aH);
      if (lastArrive(a.cnt + tile, 4))
        reduce_gate(a.P, 4, hp, 0, S0f, (unsigned*)S0hi, (unsigned*)S0lo, row0, col0);
      barT += NBLK; gbar(a.bar, barT);
    }
    { // ---- stage 1: e0 (tanh, pred s0), split x4 {7,7,7,6}
      f32x4 aC[2][2] = {}, aH[2][2] = {};
      int i0 = by * 6 + imin(by, 3), len = 6 + (by < 3 ? 1 : 0);
      gemm_bf(sh, S0hi, S0lo, a.Wsh, a.Wsl, i0, i0 + len, row0, col0, aC, aH);
      writeP(a.P + (size_t)by * PST, row0, col0, aC, aH);
      if (lastArrive(a.cnt + tile, 4))
        reduce_gate(a.P, 4, S0f, 0, S1f, (unsigned*)S1hi, (unsigned*)S1lo, row0, col0);
      barT += NBLK; gbar(a.bar, barT);
    }
    { // ---- stage 2: e1(relu)->S2, e2(relu)->S3, e3(ident)->S4; A=S1, split x4 each
      int i0 = by * 6 + imin(by, 3), len = 6 + (by < 3 ? 1 : 0);
      for (int e = 0; e < 3; ++e) {
        f32x4 aC[2][2] = {}, aH[2][2] = {};
        gemm_bf(sh, S1hi, S1lo, a.Wsh + (size_t)(1 + e) * WES, a.Wsl + (size_t)(1 + e) * WES,
                i0, i0 + len, row0, col0, aC, aH);
        writeP(a.P + (size_t)(e * 4 + by) * PST, row0, col0, aC, aH);
        if (lastArrive(a.cnt + e * 56 + tile, 4)) {
          if (e == 0)
            reduce_gate(a.P, 4, S1f, 1, S2f, (unsigned*)S2hi, (unsigned*)S2lo, row0, col0);
          else if (e == 1)
            reduce_gate(a.P + 4 * PST, 4, S1f, 1, S3f, (unsigned*)S3hi, (unsigned*)S3lo, row0, col0);
          else
            reduce_gate(a.P + 8 * PST, 4, S1f, 3, S4f, nullptr, nullptr, row0, col0);
        }
      }
      barT += NBLK; gbar(a.bar, barT);
    }
    { // ---- stage 3: e4 (A=S2)->S5+hi/lo, e6 (A=S3)->S7; by -> (edge, split x2 {14,13})
      f32x4 aC[2][2] = {}, aH[2][2] = {};
      int e = by >> 1, sp = by & 1;
      int i0 = sp * 14, len = sp ? 13 : 14;
      const unsigned short* Ah = e ? S3hi : S2hi;
      const unsigned short* Al = e ? S3lo : S2lo;
      int widx = e ? 6 : 4;
      gemm_bf(sh, Ah, Al, a.Wsh + (size_t)widx * WES, a.Wsl + (size_t)widx * WES,
              i0, i0 + len, row0, col0, aC, aH);
      writeP(a.P + (size_t)(e * 2 + sp) * PST, row0, col0, aC, aH);
      if (lastArrive(a.cnt + e * 56 + tile, 2)) {
        if (e == 0)
          reduce_gate(a.P, 2, S2f, 0, S5f, (unsigned*)S5hi, (unsigned*)S5lo, row0, col0);
        else
          reduce_gate(a.P + 2 * PST, 2, S3f, 0, S7f, nullptr, nullptr, row0, col0);
      }
      barT += NBLK; gbar(a.bar, barT);
    }
    { // ---- stage 4: e5/e7 (A=S5) + fused gates + mean -> out[t]
      f32x4 aC[2][2] = {}, aH[2][2] = {};
      int e = by >> 1, sp = by & 1;
      int i0 = sp * 14, len = sp ? 13 : 14;
      int widx = e ? 7 : 5;
      gemm_bf(sh, S5hi, S5lo, a.Wsh + (size_t)widx * WES, a.Wsl + (size_t)widx * WES,
              i0, i0 + len, row0, col0, aC, aH);
      writeP(a.P + (size_t)(e * 2 + sp) * PST, row0, col0, aC, aH);
      if (lastArrive(a.cnt + tile, 4))
        reduce_fin(a.P, S1f, S2f, S3f, S4f, S5f, S7f,
                   a.out + (size_t)t * SSZ,
                   (t == 69) ? a.out + (size_t)70 * SSZ : nullptr, row0, col0);
      barT += NBLK; gbar(a.bar, barT);
    }
  }
}

extern "C" void kernel_launch(void* const* d_in, const int* in_sizes, int n_in,
                              void* d_out, int out_size, void* d_ws, size_t ws_size,
                              hipStream_t stream) {
  (void)in_sizes; (void)n_in; (void)out_size; (void)ws_size;
  const float* X  = (const float*)d_in[0];
  const float* H0 = (const float*)d_in[1];
  const float* W0 = (const float*)d_in[2];
  const float* Ws = (const float*)d_in[3];
  float* out = (float*)d_out;

  char* w = (char*)d_ws;
  float* Sf = (float*)w;
  size_t off = (size_t)7 * SSZ * sizeof(float);
  unsigned short* Shi = (unsigned short*)(w + off); off += 5 * SBSZ * 2;
  unsigned short* Slo = (unsigned short*)(w + off); off += 5 * SBSZ * 2;
  unsigned short* W0h = (unsigned short*)(w + off); off += (size_t)1700 * KP0 * 2;
  unsigned short* W0l = (unsigned short*)(w + off); off += (size_t)1700 * KP0 * 2;
  unsigned short* Wsh = (unsigned short*)(w + off); off += (size_t)8 * WES * 2;
  unsigned short* Wsl = (unsigned short*)(w + off); off += (size_t)8 * WES * 2;
  float* P = (float*)(w + off); off += (size_t)12 * PST * sizeof(float);
  int* bar = (int*)(w + off); off += 256;          // 1 int + pad
  int* cnt = (int*)(w + off);                      // 256 ints

  // upfront: weight split+transpose, sync-state zeroing (3 launches)
  { TransCfg c{W0, W0h, W0l, 0, 0, 1700, 1700, KP0};
    k_wsplit<<<dim3(KP0 / 32, 54, 1), dim3(32, 8), 0, stream>>>(c); }
  { TransCfg c{Ws, Wsh, Wsl, (long)850 * 1700, (long)WES, 850, 1700, KP1};
    k_wsplit<<<dim3(KP1 / 32, 54, 8), dim3(32, 8), 0, stream>>>(c); }
  k_init<<<dim3(1), dim3(256), 0, stream>>>(bar, cnt);

  // the entire 70-step recurrence: ONE launch, 224 co-resident blocks
  MegaArgs a{X, H0, out, W0h, W0l, Wsh, Wsl, Sf, Shi, Slo, P, bar, cnt};
  k_mega<<<dim3(56, 4), dim3(256), 0, stream>>>(a);
}